// Round 1
// baseline (6195.838 us; speedup 1.0000x reference)
//
#include <hip/hip_runtime.h>
#include <math.h>

#define T 2048
#define D 512
#define NH 8
#define DH 64
#define NB 4
#define NTOK (NB * T)   // 8192
#define NEG_BIG -1e30f

// ---------------- Kernel A: LayerNorm + key-padding mask + masked labels ----
__global__ __launch_bounds__(256) void ln_kernel(
    const float* __restrict__ embs, const float* __restrict__ labels,
    const float* __restrict__ g, const float* __restrict__ bb,
    float* __restrict__ x, float* __restrict__ wm, float* __restrict__ kpmf)
{
    __shared__ float sm[8];
    int n = blockIdx.x;
    int tid = threadIdx.x;
    int lane = tid & 63, wid = tid >> 6;
    const float* e = embs + (size_t)n * D;
    float v0 = e[tid], v1 = e[tid + 256];

    float s = v0 + v1;
    #pragma unroll
    for (int o = 32; o; o >>= 1) s += __shfl_xor(s, o, 64);
    if (lane == 0) sm[wid] = s;
    __syncthreads();
    float mu = (sm[0] + sm[1] + sm[2] + sm[3]) * (1.0f / D);
    __syncthreads();

    float d0 = v0 - mu, d1 = v1 - mu;
    float ss = d0 * d0 + d1 * d1;
    #pragma unroll
    for (int o = 32; o; o >>= 1) ss += __shfl_xor(ss, o, 64);
    if (lane == 0) sm[wid] = ss;
    __syncthreads();
    float var = (sm[0] + sm[1] + sm[2] + sm[3]) * (1.0f / D);
    float rstd = rsqrtf(var + 1e-5f);

    float x0 = d0 * rstd * g[tid] + bb[tid];
    float x1 = d1 * rstd * g[tid + 256] + bb[tid + 256];
    x[(size_t)n * D + tid] = x0;
    x[(size_t)n * D + tid + 256] = x1;

    __syncthreads();
    float as = fabsf(x0) + fabsf(x1);
    #pragma unroll
    for (int o = 32; o; o >>= 1) as += __shfl_xor(as, o, 64);
    if (lane == 0) sm[wid] = as;
    __syncthreads();
    if (tid == 0) {
        float abssum = sm[0] + sm[1] + sm[2] + sm[3];
        int kpm = (abssum <= 1e-6f);
        kpmf[n] = kpm ? 1.0f : 0.0f;
        wm[n] = kpm ? 0.0f : labels[n];
    }
}

// ---------------- Kernel B: fused QKV projection (fp32 tiled GEMM) ----------
// qkv[n][j] = sum_d x[n][d] * W[j][d] + b[j]; scatter into q/kt/v layouts.
// q : [bh][t][dh]  (pre-scaled by 1/sqrt(dh))
// kt: [bh][dh][t]
// v : [bh][t][dh]
__global__ __launch_bounds__(256) void qkv_kernel(
    const float* __restrict__ x, const float* __restrict__ W,
    const float* __restrict__ bias, float* __restrict__ q,
    float* __restrict__ kt, float* __restrict__ v)
{
    __shared__ __align__(16) float As[32][68];
    __shared__ __align__(16) float Bs[32][68];
    int tid = threadIdx.x;
    int m0 = blockIdx.x * 64;
    int j0 = blockIdx.y * 64;
    int tm = (tid & 15) * 4, tn = (tid >> 4) * 4;
    float acc[4][4] = {};
    int lrow = tid >> 3;          // 0..31
    int lk4 = (tid & 7) * 4;      // 0,4,...,28

    for (int k0 = 0; k0 < D; k0 += 32) {
        #pragma unroll
        for (int p = 0; p < 2; ++p) {
            int row = lrow + p * 32;
            float4 a4 = *(const float4*)(x + (size_t)(m0 + row) * D + k0 + lk4);
            As[lk4 + 0][row] = a4.x; As[lk4 + 1][row] = a4.y;
            As[lk4 + 2][row] = a4.z; As[lk4 + 3][row] = a4.w;
            float4 b4 = *(const float4*)(W + (size_t)(j0 + row) * D + k0 + lk4);
            Bs[lk4 + 0][row] = b4.x; Bs[lk4 + 1][row] = b4.y;
            Bs[lk4 + 2][row] = b4.z; Bs[lk4 + 3][row] = b4.w;
        }
        __syncthreads();
        #pragma unroll
        for (int k = 0; k < 32; ++k) {
            float4 a4 = *(const float4*)&As[k][tm];
            float4 b4 = *(const float4*)&Bs[k][tn];
            float a[4] = {a4.x, a4.y, a4.z, a4.w};
            float b[4] = {b4.x, b4.y, b4.z, b4.w};
            #pragma unroll
            for (int i = 0; i < 4; ++i)
                #pragma unroll
                for (int j = 0; j < 4; ++j) acc[i][j] += a[i] * b[j];
        }
        __syncthreads();
    }

    // scatter (part/h uniform per block since j0 is 64-aligned)
    #pragma unroll
    for (int i = 0; i < 4; ++i) {
        int tok = m0 + tm + i;
        int b_ = tok >> 11, t = tok & (T - 1);
        #pragma unroll
        for (int j = 0; j < 4; ++j) {
            int col = j0 + tn + j;
            float val = acc[i][j] + bias[col];
            int part = col >> 9;       // 0=q,1=k,2=v
            int cc = col & 511;
            int h = cc >> 6, dh = cc & 63;
            int bh = b_ * NH + h;
            if (part == 0)      q[((size_t)bh * T + t) * DH + dh] = val * 0.125f;
            else if (part == 1) kt[((size_t)bh * DH + dh) * T + t] = val;
            else                v[((size_t)bh * T + t) * DH + dh] = val;
        }
    }
}

// ---------------- Kernel C: flash attention, 1 wave = 8 query rows ----------
__global__ __launch_bounds__(256) void attn_kernel(
    const float* __restrict__ q, const float* __restrict__ kt,
    const float* __restrict__ v, const float* __restrict__ wm,
    const float* __restrict__ kpmf, const float* __restrict__ alpha_p,
    const float* __restrict__ beta_p, float* __restrict__ o)
{
    int wave = threadIdx.x >> 6, lane = threadIdx.x & 63;
    int wt = blockIdx.x * 4 + wave;   // 0..8191
    int r0 = wt * 8;                  // first of 8 query rows (same bh)
    int bh = r0 >> 11;
    int b_ = bh >> 3;
    float alpha = alpha_p[0], beta = beta_p[0];

    float ql[8], m[8], l[8], acc[8];
    #pragma unroll
    for (int r = 0; r < 8; ++r) {
        ql[r] = q[(size_t)(r0 + r) * DH + lane];
        m[r] = -3.0e38f; l[r] = 0.f; acc[r] = 0.f;
    }
    const float* ktb = kt + (size_t)bh * DH * T;
    const float* vb  = v  + (size_t)bh * T * DH;
    const float* wmb = wm + b_ * T;
    const float* kpb = kpmf + b_ * T;

    for (int j0 = 0; j0 < T; j0 += 64) {
        int key = j0 + lane;
        float s[8] = {};
        #pragma unroll
        for (int d = 0; d < DH; ++d) {
            float kd = ktb[(size_t)d * T + key];
            #pragma unroll
            for (int r = 0; r < 8; ++r) s[r] += __shfl(ql[r], d, 64) * kd;
        }
        float bias = alpha * wmb[key] + beta;
        bool msk = kpb[key] != 0.f;
        float p[8];
        #pragma unroll
        for (int r = 0; r < 8; ++r) {
            float sr = msk ? NEG_BIG : (s[r] + bias);
            float tmx = sr;
            #pragma unroll
            for (int off = 32; off; off >>= 1) tmx = fmaxf(tmx, __shfl_xor(tmx, off, 64));
            float mn = fmaxf(m[r], tmx);
            float sc = __expf(m[r] - mn);
            float pr = __expf(sr - mn);
            float ps = pr;
            #pragma unroll
            for (int off = 32; off; off >>= 1) ps += __shfl_xor(ps, off, 64);
            l[r] = l[r] * sc + ps;
            acc[r] *= sc;
            m[r] = mn;
            p[r] = pr;
        }
        const float* vrow = vb + (size_t)j0 * DH + lane;
        #pragma unroll
        for (int j = 0; j < 64; ++j) {
            float vj = vrow[(size_t)j * DH];
            #pragma unroll
            for (int r = 0; r < 8; ++r) acc[r] += __shfl(p[r], j, 64) * vj;
        }
    }
    #pragma unroll
    for (int r = 0; r < 8; ++r) o[(size_t)(r0 + r) * DH + lane] = acc[r] / l[r];
}

// ---------------- Kernel D: masked sum of attention output over T -----------
// S[b][h*64+dh] = sum_t o[bh][t][dh] * (1 - kpmf[b][t])
__global__ __launch_bounds__(256) void pool_kernel(
    const float* __restrict__ o, const float* __restrict__ kpmf,
    float* __restrict__ S)
{
    __shared__ float sm[4][64];
    int bh = blockIdx.x;          // 0..31
    int b_ = bh >> 3;
    int lane = threadIdx.x & 63, chunk = threadIdx.x >> 6;
    const float* ob = o + (size_t)bh * T * DH;
    const float* kp = kpmf + b_ * T;
    float acc = 0.f;
    for (int t = chunk * 512; t < (chunk + 1) * 512; ++t)
        acc += ob[(size_t)t * DH + lane] * (1.0f - kp[t]);
    sm[chunk][lane] = acc;
    __syncthreads();
    if (chunk == 0) {
        float r = sm[0][lane] + sm[1][lane] + sm[2][lane] + sm[3][lane];
        int h = bh & 7;
        S[b_ * D + h * DH + lane] = r;
    }
}

// ---------------- Kernel E: out-projection of pooled vector + bias ----------
// pooled[b][d] = (S[b] . Wo[d] + bo[d]*cnt) / max(cnt,1)
__global__ __launch_bounds__(256) void out_kernel(
    const float* __restrict__ S, const float* __restrict__ kpmf,
    const float* __restrict__ Wo, const float* __restrict__ bo,
    float* __restrict__ out)
{
    __shared__ float Sl[512];
    __shared__ float cs[4];
    int b_ = blockIdx.x;
    int tid = threadIdx.x;
    Sl[tid] = S[b_ * D + tid];
    Sl[tid + 256] = S[b_ * D + tid + 256];
    const float* kp = kpmf + b_ * T;
    float c = 0.f;
    for (int t = tid; t < T; t += 256) c += kp[t];
    #pragma unroll
    for (int o = 32; o; o >>= 1) c += __shfl_xor(c, o, 64);
    if ((tid & 63) == 0) cs[tid >> 6] = c;
    __syncthreads();
    float masked = cs[0] + cs[1] + cs[2] + cs[3];
    float cnt = (float)T - masked;
    float inv = 1.0f / fmaxf(cnt, 1.0f);
    #pragma unroll
    for (int p = 0; p < 2; ++p) {
        int d = tid + p * 256;
        const float4* wr4 = (const float4*)(Wo + (size_t)d * D);
        float dot = 0.f;
        for (int k4 = 0; k4 < D / 4; ++k4) {
            float4 w4 = wr4[k4];
            dot += Sl[4 * k4 + 0] * w4.x + Sl[4 * k4 + 1] * w4.y +
                   Sl[4 * k4 + 2] * w4.z + Sl[4 * k4 + 3] * w4.w;
        }
        out[b_ * D + d] = (dot + bo[d] * cnt) * inv;
    }
}

extern "C" void kernel_launch(void* const* d_in, const int* in_sizes, int n_in,
                              void* d_out, int out_size, void* d_ws, size_t ws_size,
                              hipStream_t stream) {
    const float* embs   = (const float*)d_in[0];
    const float* labels = (const float*)d_in[1];
    const float* ln_g   = (const float*)d_in[2];
    const float* ln_b   = (const float*)d_in[3];
    const float* ipw    = (const float*)d_in[4];
    const float* ipb    = (const float*)d_in[5];
    const float* ow     = (const float*)d_in[6];
    const float* obb    = (const float*)d_in[7];
    const float* alpha  = (const float*)d_in[8];
    const float* beta   = (const float*)d_in[9];
    float* out = (float*)d_out;

    float* ws   = (float*)d_ws;
    float* x    = ws;                  // 8192*512
    float* q    = x  + (size_t)NTOK * D;
    float* kt   = q  + (size_t)NTOK * D;
    float* v    = kt + (size_t)NTOK * D;
    float* o    = v  + (size_t)NTOK * D;
    float* wmb  = o  + (size_t)NTOK * D;   // 8192
    float* kpmf = wmb + NTOK;              // 8192
    float* S    = kpmf + NTOK;             // 2048

    ln_kernel<<<NTOK, 256, 0, stream>>>(embs, labels, ln_g, ln_b, x, wmb, kpmf);
    dim3 gq(NTOK / 64, (3 * D) / 64);
    qkv_kernel<<<gq, 256, 0, stream>>>(x, ipw, ipb, q, kt, v);
    attn_kernel<<<(NB * NH * T / 8) / 4, 256, 0, stream>>>(q, kt, v, wmb, kpmf, alpha, beta, o);
    pool_kernel<<<NB * NH, 256, 0, stream>>>(o, kpmf, S);
    out_kernel<<<NB, 256, 0, stream>>>(S, kpmf, ow, obb, out);
}

// Round 2
// 861.627 us; speedup vs baseline: 7.1909x; 7.1909x over previous
//
#include <hip/hip_runtime.h>
#include <math.h>

#define T 2048
#define D 512
#define NH 8
#define DH 64
#define NB 4
#define NTOK (NB * T)   // 8192
#define NEG_BIG -2e30f

// ---------------- Kernel A: LayerNorm + key-padding mask + masked labels ----
__global__ __launch_bounds__(256) void ln_kernel(
    const float* __restrict__ embs, const float* __restrict__ labels,
    const float* __restrict__ g, const float* __restrict__ bb,
    float* __restrict__ x, float* __restrict__ wm, float* __restrict__ kpmf)
{
    __shared__ float sm[8];
    int n = blockIdx.x;
    int tid = threadIdx.x;
    int lane = tid & 63, wid = tid >> 6;
    const float* e = embs + (size_t)n * D;
    float v0 = e[tid], v1 = e[tid + 256];

    float s = v0 + v1;
    #pragma unroll
    for (int o = 32; o; o >>= 1) s += __shfl_xor(s, o, 64);
    if (lane == 0) sm[wid] = s;
    __syncthreads();
    float mu = (sm[0] + sm[1] + sm[2] + sm[3]) * (1.0f / D);
    __syncthreads();

    float d0 = v0 - mu, d1 = v1 - mu;
    float ss = d0 * d0 + d1 * d1;
    #pragma unroll
    for (int o = 32; o; o >>= 1) ss += __shfl_xor(ss, o, 64);
    if (lane == 0) sm[wid] = ss;
    __syncthreads();
    float var = (sm[0] + sm[1] + sm[2] + sm[3]) * (1.0f / D);
    float rstd = rsqrtf(var + 1e-5f);

    float x0 = d0 * rstd * g[tid] + bb[tid];
    float x1 = d1 * rstd * g[tid + 256] + bb[tid + 256];
    x[(size_t)n * D + tid] = x0;
    x[(size_t)n * D + tid + 256] = x1;

    __syncthreads();
    float as = fabsf(x0) + fabsf(x1);
    #pragma unroll
    for (int o = 32; o; o >>= 1) as += __shfl_xor(as, o, 64);
    if (lane == 0) sm[wid] = as;
    __syncthreads();
    if (tid == 0) {
        float abssum = sm[0] + sm[1] + sm[2] + sm[3];
        int kpm = (abssum <= 1e-6f);
        kpmf[n] = kpm ? 1.0f : 0.0f;
        wm[n] = kpm ? 0.0f : labels[n];
    }
}

// ---------------- Kernel B: fused QKV projection (fp32 tiled GEMM) ----------
// qkv[n][j] = sum_d x[n][d] * W[j][d] + b[j]; scatter into layouts:
// qt: [bh][dh][t]  (pre-scaled by 1/sqrt(dh), transposed like kt)
// kt: [bh][dh][t]
// v : [bh][t][dh]
__global__ __launch_bounds__(256) void qkv_kernel(
    const float* __restrict__ x, const float* __restrict__ W,
    const float* __restrict__ bias, float* __restrict__ qt,
    float* __restrict__ kt, float* __restrict__ v)
{
    __shared__ __align__(16) float As[32][68];
    __shared__ __align__(16) float Bs[32][68];
    int tid = threadIdx.x;
    int m0 = blockIdx.x * 64;
    int j0 = blockIdx.y * 64;
    int tm = (tid & 15) * 4, tn = (tid >> 4) * 4;
    float acc[4][4] = {};
    int lrow = tid >> 3;          // 0..31
    int lk4 = (tid & 7) * 4;      // 0,4,...,28

    for (int k0 = 0; k0 < D; k0 += 32) {
        #pragma unroll
        for (int p = 0; p < 2; ++p) {
            int row = lrow + p * 32;
            float4 a4 = *(const float4*)(x + (size_t)(m0 + row) * D + k0 + lk4);
            As[lk4 + 0][row] = a4.x; As[lk4 + 1][row] = a4.y;
            As[lk4 + 2][row] = a4.z; As[lk4 + 3][row] = a4.w;
            float4 b4 = *(const float4*)(W + (size_t)(j0 + row) * D + k0 + lk4);
            Bs[lk4 + 0][row] = b4.x; Bs[lk4 + 1][row] = b4.y;
            Bs[lk4 + 2][row] = b4.z; Bs[lk4 + 3][row] = b4.w;
        }
        __syncthreads();
        #pragma unroll
        for (int k = 0; k < 32; ++k) {
            float4 a4 = *(const float4*)&As[k][tm];
            float4 b4 = *(const float4*)&Bs[k][tn];
            float a[4] = {a4.x, a4.y, a4.z, a4.w};
            float b[4] = {b4.x, b4.y, b4.z, b4.w};
            #pragma unroll
            for (int i = 0; i < 4; ++i)
                #pragma unroll
                for (int j = 0; j < 4; ++j) acc[i][j] += a[i] * b[j];
        }
        __syncthreads();
    }

    #pragma unroll
    for (int i = 0; i < 4; ++i) {
        int tok = m0 + tm + i;
        int b_ = tok >> 11, t = tok & (T - 1);
        #pragma unroll
        for (int j = 0; j < 4; ++j) {
            int col = j0 + tn + j;
            float val = acc[i][j] + bias[col];
            int part = col >> 9;       // 0=q,1=k,2=v
            int cc = col & 511;
            int h = cc >> 6, dh = cc & 63;
            int bh = b_ * NH + h;
            if (part == 0)      qt[((size_t)bh * DH + dh) * T + t] = val * 0.125f;
            else if (part == 1) kt[((size_t)bh * DH + dh) * T + t] = val;
            else                v[((size_t)bh * T + t) * DH + dh] = val;
        }
    }
}

// ---------------- Kernel C: LDS-tiled flash attention ----------------------
// Block = 64-query tile of one bh. 256 threads, 4x4 microtile per thread.
__global__ __launch_bounds__(256) void attn_kernel(
    const float* __restrict__ qt, const float* __restrict__ kt,
    const float* __restrict__ v, const float* __restrict__ wm,
    const float* __restrict__ kpmf, const float* __restrict__ alpha_p,
    const float* __restrict__ beta_p, float* __restrict__ o)
{
    __shared__ __align__(16) float Qs[64][68];  // [dh][row]
    __shared__ __align__(16) float Ks[64][68];  // [dh][key]
    __shared__ __align__(16) float Vs[64][68];  // [key][dh]
    __shared__ __align__(16) float Ps[64][68];  // [key][row]
    __shared__ float bs[64];                    // bias-or-neg per key

    int tid = threadIdx.x;
    int lane = tid & 63, wave = tid >> 6;
    int bh = blockIdx.x >> 5;
    int q0 = (blockIdx.x & 31) * 64;
    int b_ = bh >> 3;
    float alpha = alpha_p[0], beta = beta_p[0];

    int lr = tid >> 4;          // 0..15 (load row base)
    int lc4 = (tid & 15) * 4;   // load col*4

    const float* qb = qt + (size_t)bh * DH * T;
    const float* kb = kt + (size_t)bh * DH * T;
    const float* vb = v + (size_t)bh * T * DH;
    const float* wmb = wm + b_ * T;
    const float* kpb = kpmf + b_ * T;

    // load Q tile once
    #pragma unroll
    for (int rep = 0; rep < 4; ++rep) {
        int row = lr + rep * 16;   // dh index
        *(float4*)&Qs[row][lc4] = *(const float4*)(qb + (size_t)row * T + q0 + lc4);
    }

    int r0 = wave * 16 + (lane >> 4) * 4;  // query rows owned
    int c0 = (lane & 15) * 4;              // key cols / dh cols owned

    float accO[4][4] = {};
    float m[4], l[4];
    #pragma unroll
    for (int i = 0; i < 4; ++i) { m[i] = -3.0e38f; l[i] = 0.f; }

    for (int j0 = 0; j0 < T; j0 += 64) {
        // load K, V tiles + key bias
        #pragma unroll
        for (int rep = 0; rep < 4; ++rep) {
            int row = lr + rep * 16;
            *(float4*)&Ks[row][lc4] = *(const float4*)(kb + (size_t)row * T + j0 + lc4);
            *(float4*)&Vs[row][lc4] = *(const float4*)(vb + (size_t)(j0 + row) * DH + lc4);
        }
        if (tid < 64) {
            int key = j0 + tid;
            bs[tid] = (kpb[key] != 0.f) ? NEG_BIG : (alpha * wmb[key] + beta);
        }
        __syncthreads();

        // S = Q.K^T  (rows r0.., cols c0..)
        float s[4][4] = {};
        #pragma unroll
        for (int dh = 0; dh < DH; ++dh) {
            float4 a4 = *(const float4*)&Qs[dh][r0];
            float4 b4 = *(const float4*)&Ks[dh][c0];
            float a[4] = {a4.x, a4.y, a4.z, a4.w};
            float b[4] = {b4.x, b4.y, b4.z, b4.w};
            #pragma unroll
            for (int i = 0; i < 4; ++i)
                #pragma unroll
                for (int j = 0; j < 4; ++j) s[i][j] += a[i] * b[j];
        }
        // bias / mask
        #pragma unroll
        for (int j = 0; j < 4; ++j) {
            float bj = bs[c0 + j];
            #pragma unroll
            for (int i = 0; i < 4; ++i) s[i][j] += bj;
        }
        // online softmax (row reduction across lane bits 0..3)
        float p[4][4], sc[4];
        #pragma unroll
        for (int i = 0; i < 4; ++i) {
            float mx = fmaxf(fmaxf(s[i][0], s[i][1]), fmaxf(s[i][2], s[i][3]));
            #pragma unroll
            for (int off = 1; off <= 8; off <<= 1) mx = fmaxf(mx, __shfl_xor(mx, off, 64));
            float mn = fmaxf(m[i], mx);
            sc[i] = __expf(m[i] - mn);
            float ps = 0.f;
            #pragma unroll
            for (int j = 0; j < 4; ++j) { p[i][j] = __expf(s[i][j] - mn); ps += p[i][j]; }
            #pragma unroll
            for (int off = 1; off <= 8; off <<= 1) ps += __shfl_xor(ps, off, 64);
            l[i] = l[i] * sc[i] + ps;
            m[i] = mn;
        }
        // write P transposed: Ps[key][row]
        #pragma unroll
        for (int j = 0; j < 4; ++j) {
            float4 pw = make_float4(p[0][j], p[1][j], p[2][j], p[3][j]);
            *(float4*)&Ps[c0 + j][r0] = pw;
        }
        __syncthreads();

        // O = O*sc + P.V
        #pragma unroll
        for (int i = 0; i < 4; ++i)
            #pragma unroll
            for (int j = 0; j < 4; ++j) accO[i][j] *= sc[i];
        #pragma unroll
        for (int key = 0; key < 64; ++key) {
            float4 a4 = *(const float4*)&Ps[key][r0];
            float4 b4 = *(const float4*)&Vs[key][c0];
            float a[4] = {a4.x, a4.y, a4.z, a4.w};
            float b[4] = {b4.x, b4.y, b4.z, b4.w};
            #pragma unroll
            for (int i = 0; i < 4; ++i)
                #pragma unroll
                for (int j = 0; j < 4; ++j) accO[i][j] += a[i] * b[j];
        }
        __syncthreads();
    }

    // write O
    #pragma unroll
    for (int i = 0; i < 4; ++i) {
        float inv = 1.0f / l[i];
        float4 ow = make_float4(accO[i][0] * inv, accO[i][1] * inv,
                                accO[i][2] * inv, accO[i][3] * inv);
        *(float4*)(o + ((size_t)bh * T + q0 + r0 + i) * DH + c0) = ow;
    }
}

// ---------------- Kernel D: masked sum of attention output over T -----------
__global__ __launch_bounds__(256) void pool_kernel(
    const float* __restrict__ o, const float* __restrict__ kpmf,
    float* __restrict__ S)
{
    __shared__ float sm[4][64];
    int bh = blockIdx.x;          // 0..31
    int b_ = bh >> 3;
    int lane = threadIdx.x & 63, chunk = threadIdx.x >> 6;
    const float* ob = o + (size_t)bh * T * DH;
    const float* kp = kpmf + b_ * T;
    float acc = 0.f;
    for (int t = chunk * 512; t < (chunk + 1) * 512; ++t)
        acc += ob[(size_t)t * DH + lane] * (1.0f - kp[t]);
    sm[chunk][lane] = acc;
    __syncthreads();
    if (chunk == 0) {
        float r = sm[0][lane] + sm[1][lane] + sm[2][lane] + sm[3][lane];
        int h = bh & 7;
        S[b_ * D + h * DH + lane] = r;
    }
}

// ---------------- Kernel E: out-projection of pooled vector + bias ----------
__global__ __launch_bounds__(256) void out_kernel(
    const float* __restrict__ S, const float* __restrict__ kpmf,
    const float* __restrict__ Wo, const float* __restrict__ bo,
    float* __restrict__ out)
{
    __shared__ float Sl[512];
    __shared__ float cs[4];
    int b_ = blockIdx.x;
    int tid = threadIdx.x;
    Sl[tid] = S[b_ * D + tid];
    Sl[tid + 256] = S[b_ * D + tid + 256];
    const float* kp = kpmf + b_ * T;
    float c = 0.f;
    for (int t = tid; t < T; t += 256) c += kp[t];
    #pragma unroll
    for (int o = 32; o; o >>= 1) c += __shfl_xor(c, o, 64);
    if ((tid & 63) == 0) cs[tid >> 6] = c;
    __syncthreads();
    float masked = cs[0] + cs[1] + cs[2] + cs[3];
    float cnt = (float)T - masked;
    float inv = 1.0f / fmaxf(cnt, 1.0f);
    #pragma unroll
    for (int p = 0; p < 2; ++p) {
        int d = tid + p * 256;
        const float4* wr4 = (const float4*)(Wo + (size_t)d * D);
        float dot = 0.f;
        for (int k4 = 0; k4 < D / 4; ++k4) {
            float4 w4 = wr4[k4];
            dot += Sl[4 * k4 + 0] * w4.x + Sl[4 * k4 + 1] * w4.y +
                   Sl[4 * k4 + 2] * w4.z + Sl[4 * k4 + 3] * w4.w;
        }
        out[b_ * D + d] = (dot + bo[d] * cnt) * inv;
    }
}

extern "C" void kernel_launch(void* const* d_in, const int* in_sizes, int n_in,
                              void* d_out, int out_size, void* d_ws, size_t ws_size,
                              hipStream_t stream) {
    const float* embs   = (const float*)d_in[0];
    const float* labels = (const float*)d_in[1];
    const float* ln_g   = (const float*)d_in[2];
    const float* ln_b   = (const float*)d_in[3];
    const float* ipw    = (const float*)d_in[4];
    const float* ipb    = (const float*)d_in[5];
    const float* ow     = (const float*)d_in[6];
    const float* obb    = (const float*)d_in[7];
    const float* alpha  = (const float*)d_in[8];
    const float* beta   = (const float*)d_in[9];
    float* out = (float*)d_out;

    float* ws   = (float*)d_ws;
    float* x    = ws;                  // 8192*512
    float* qt   = x  + (size_t)NTOK * D;
    float* kt   = qt + (size_t)NTOK * D;
    float* v    = kt + (size_t)NTOK * D;
    float* o    = v  + (size_t)NTOK * D;
    float* wmb  = o  + (size_t)NTOK * D;   // 8192
    float* kpmf = wmb + NTOK;              // 8192
    float* S    = kpmf + NTOK;             // 2048

    ln_kernel<<<NTOK, 256, 0, stream>>>(embs, labels, ln_g, ln_b, x, wmb, kpmf);
    dim3 gq(NTOK / 64, (3 * D) / 64);
    qkv_kernel<<<gq, 256, 0, stream>>>(x, ipw, ipb, qt, kt, v);
    attn_kernel<<<NB * NH * (T / 64), 256, 0, stream>>>(qt, kt, v, wmb, kpmf, alpha, beta, o);
    pool_kernel<<<NB * NH, 256, 0, stream>>>(o, kpmf, S);
    out_kernel<<<NB, 256, 0, stream>>>(S, kpmf, ow, obb, out);
}

// Round 3
// 291.447 us; speedup vs baseline: 21.2589x; 2.9564x over previous
//
#include <hip/hip_runtime.h>
#include <math.h>

#define T 2048
#define D 512
#define NH 8
#define DH 64
#define NB 4
#define NTOK (NB * T)   // 8192
#define NEG_BIG -2e30f

using bf16x8 = __attribute__((ext_vector_type(8))) short;
using f32x4  = __attribute__((ext_vector_type(4))) float;

static __device__ __forceinline__ unsigned short f2bf(float f) {
    union { float f; unsigned u; } v; v.f = f;
    unsigned r = v.u + 0x7fffu + ((v.u >> 16) & 1u);   // RNE
    return (unsigned short)(r >> 16);
}

// ---------------- Kernel A: LayerNorm + mask + masked labels (bf16 x out) ---
__global__ __launch_bounds__(256) void ln_kernel(
    const float* __restrict__ embs, const float* __restrict__ labels,
    const float* __restrict__ g, const float* __restrict__ bb,
    unsigned short* __restrict__ xb, float* __restrict__ wm,
    float* __restrict__ kpmf)
{
    __shared__ float sm[8];
    int n = blockIdx.x;
    int tid = threadIdx.x;
    int lane = tid & 63, wid = tid >> 6;
    const float* e = embs + (size_t)n * D;
    float v0 = e[tid], v1 = e[tid + 256];

    float s = v0 + v1;
    #pragma unroll
    for (int o = 32; o; o >>= 1) s += __shfl_xor(s, o, 64);
    if (lane == 0) sm[wid] = s;
    __syncthreads();
    float mu = (sm[0] + sm[1] + sm[2] + sm[3]) * (1.0f / D);
    __syncthreads();

    float d0 = v0 - mu, d1 = v1 - mu;
    float ss = d0 * d0 + d1 * d1;
    #pragma unroll
    for (int o = 32; o; o >>= 1) ss += __shfl_xor(ss, o, 64);
    if (lane == 0) sm[wid] = ss;
    __syncthreads();
    float var = (sm[0] + sm[1] + sm[2] + sm[3]) * (1.0f / D);
    float rstd = rsqrtf(var + 1e-5f);

    float x0 = d0 * rstd * g[tid] + bb[tid];
    float x1 = d1 * rstd * g[tid + 256] + bb[tid + 256];
    xb[(size_t)n * D + tid] = f2bf(x0);
    xb[(size_t)n * D + tid + 256] = f2bf(x1);

    __syncthreads();
    float as = fabsf(x0) + fabsf(x1);
    #pragma unroll
    for (int o = 32; o; o >>= 1) as += __shfl_xor(as, o, 64);
    if (lane == 0) sm[wid] = as;
    __syncthreads();
    if (tid == 0) {
        float abssum = sm[0] + sm[1] + sm[2] + sm[3];
        int kpm = (abssum <= 1e-6f);
        kpmf[n] = kpm ? 1.0f : 0.0f;
        wm[n] = kpm ? 0.0f : labels[n];
    }
}

// ---------------- W -> bf16 conversion --------------------------------------
__global__ __launch_bounds__(256) void wconv_kernel(
    const float* __restrict__ w, unsigned short* __restrict__ wb)
{
    int i = (blockIdx.x * 256 + threadIdx.x) * 4;
    float4 f = *(const float4*)(w + i);
    ushort4 u;
    u.x = f2bf(f.x); u.y = f2bf(f.y); u.z = f2bf(f.z); u.w = f2bf(f.w);
    *(ushort4*)(wb + i) = u;
}

// ---------------- Kernel B: QKV projection via bf16 MFMA --------------------
// C[tok][col] = sum_d x[tok][d]*W[col][d] + bias[col]
// q: [bh][t][dh] bf16 (x0.125), k: [bh][t][dh] bf16, vt: [bh][dh][t] bf16
__global__ __launch_bounds__(256) void qkv_mfma(
    const unsigned short* __restrict__ xb, const unsigned short* __restrict__ wb,
    const float* __restrict__ bias, unsigned short* __restrict__ q,
    unsigned short* __restrict__ k, unsigned short* __restrict__ vt)
{
    __shared__ __align__(16) unsigned short As[64][72];
    __shared__ __align__(16) unsigned short Bs[64][72];
    int tid = threadIdx.x;
    int m0 = blockIdx.x * 64, j0 = blockIdx.y * 64;
    int wave = tid >> 6, lane = tid & 63, quad = lane >> 4, lm = lane & 15;
    int lr = tid >> 3, lseg = (tid & 7) * 8;

    f32x4 acc[4] = {{0.f,0.f,0.f,0.f},{0.f,0.f,0.f,0.f},
                    {0.f,0.f,0.f,0.f},{0.f,0.f,0.f,0.f}};

    for (int k0 = 0; k0 < D; k0 += 64) {
        #pragma unroll
        for (int p = 0; p < 2; ++p) {
            int row = lr + p * 32;
            *(uint4*)&As[row][lseg] = *(const uint4*)(xb + (size_t)(m0 + row) * D + k0 + lseg);
            *(uint4*)&Bs[row][lseg] = *(const uint4*)(wb + (size_t)(j0 + row) * D + k0 + lseg);
        }
        __syncthreads();
        #pragma unroll
        for (int kk = 0; kk < 64; kk += 32) {
            bf16x8 a = *(const bf16x8*)&As[wave * 16 + lm][kk + quad * 8];
            #pragma unroll
            for (int nt = 0; nt < 4; ++nt) {
                bf16x8 b = *(const bf16x8*)&Bs[nt * 16 + lm][kk + quad * 8];
                acc[nt] = __builtin_amdgcn_mfma_f32_16x16x32_bf16(a, b, acc[nt], 0, 0, 0);
            }
        }
        __syncthreads();
    }

    int part = j0 >> 9;            // 0=q,1=k,2=v (tiles never straddle)
    int h = (j0 & 511) >> 6;
    #pragma unroll
    for (int nt = 0; nt < 4; ++nt) {
        int dh = nt * 16 + lm;
        float bcol = bias[j0 + nt * 16 + lm];
        #pragma unroll
        for (int r = 0; r < 4; ++r) {
            int tok = m0 + wave * 16 + quad * 4 + r;
            int b_ = tok >> 11, t = tok & (T - 1);
            int bh = b_ * NH + h;
            float val = acc[nt][r] + bcol;
            if (part == 0)      q[((size_t)bh * T + t) * DH + dh] = f2bf(val * 0.125f);
            else if (part == 1) k[((size_t)bh * T + t) * DH + dh] = f2bf(val);
            else                vt[((size_t)bh * DH + dh) * T + t] = f2bf(val);
        }
    }
}

// ---------------- Kernel C: flash attention via bf16 MFMA -------------------
__global__ __launch_bounds__(256) void attn_mfma(
    const unsigned short* __restrict__ q, const unsigned short* __restrict__ k,
    const unsigned short* __restrict__ vt, const float* __restrict__ wm,
    const float* __restrict__ kpmf, const float* __restrict__ alpha_p,
    const float* __restrict__ beta_p, float* __restrict__ o)
{
    __shared__ __align__(16) unsigned short Qs[64][72];   // [query][dh]
    __shared__ __align__(16) unsigned short Ks[64][72];   // [key][dh]
    __shared__ __align__(16) unsigned short Vs[64][72];   // [dh][key]
    __shared__ __align__(16) unsigned short Ps[64][72];   // [query][key]
    __shared__ float bs[64];

    int tid = threadIdx.x, wave = tid >> 6, lane = tid & 63;
    int quad = lane >> 4, lm = lane & 15;
    int bh = blockIdx.x >> 5, q0 = (blockIdx.x & 31) * 64, b_ = bh >> 3;
    float alpha = alpha_p[0], beta = beta_p[0];

    const unsigned short* qb = q + ((size_t)bh * T + q0) * DH;
    const unsigned short* kb = k + (size_t)bh * T * DH;
    const unsigned short* vb = vt + (size_t)bh * DH * T;
    const float* wmb = wm + b_ * T;
    const float* kpb = kpmf + b_ * T;
    int lr = tid >> 3, lseg = (tid & 7) * 8;

    #pragma unroll
    for (int p = 0; p < 2; ++p) {
        int row = lr + p * 32;
        *(uint4*)&Qs[row][lseg] = *(const uint4*)(qb + (size_t)row * DH + lseg);
    }
    __syncthreads();
    bf16x8 qf0 = *(const bf16x8*)&Qs[wave * 16 + lm][quad * 8];
    bf16x8 qf1 = *(const bf16x8*)&Qs[wave * 16 + lm][32 + quad * 8];

    float m_[4], l_[4];
    f32x4 accO[4] = {{0.f,0.f,0.f,0.f},{0.f,0.f,0.f,0.f},
                     {0.f,0.f,0.f,0.f},{0.f,0.f,0.f,0.f}};
    #pragma unroll
    for (int i = 0; i < 4; ++i) { m_[i] = -3.0e38f; l_[i] = 0.f; }

    for (int j0 = 0; j0 < T; j0 += 64) {
        __syncthreads();   // all waves done with previous Ks/Vs
        #pragma unroll
        for (int p = 0; p < 2; ++p) {
            int row = lr + p * 32;
            *(uint4*)&Ks[row][lseg] = *(const uint4*)(kb + (size_t)(j0 + row) * DH + lseg);
            *(uint4*)&Vs[row][lseg] = *(const uint4*)(vb + (size_t)row * T + j0 + lseg);
        }
        if (tid < 64) {
            int key = j0 + tid;
            bs[tid] = (kpb[key] != 0.f) ? NEG_BIG : (alpha * wmb[key] + beta);
        }
        __syncthreads();

        // S = Q.K^T  (C-layout: col=key=lm+16*nt, row=quad*4+reg)
        f32x4 s[4] = {{0.f,0.f,0.f,0.f},{0.f,0.f,0.f,0.f},
                      {0.f,0.f,0.f,0.f},{0.f,0.f,0.f,0.f}};
        #pragma unroll
        for (int nt = 0; nt < 4; ++nt) {
            bf16x8 b0 = *(const bf16x8*)&Ks[nt * 16 + lm][quad * 8];
            bf16x8 b1 = *(const bf16x8*)&Ks[nt * 16 + lm][32 + quad * 8];
            s[nt] = __builtin_amdgcn_mfma_f32_16x16x32_bf16(qf0, b0, s[nt], 0, 0, 0);
            s[nt] = __builtin_amdgcn_mfma_f32_16x16x32_bf16(qf1, b1, s[nt], 0, 0, 0);
        }
        #pragma unroll
        for (int nt = 0; nt < 4; ++nt) {
            float bj = bs[nt * 16 + lm];
            #pragma unroll
            for (int r = 0; r < 4; ++r) s[nt][r] += bj;
        }
        // online softmax; row r owned by 16-lane group (lane bits 0..3 vary)
        float p_[4][4], sc[4];
        #pragma unroll
        for (int r = 0; r < 4; ++r) {
            float mx = fmaxf(fmaxf(s[0][r], s[1][r]), fmaxf(s[2][r], s[3][r]));
            #pragma unroll
            for (int off = 1; off <= 8; off <<= 1) mx = fmaxf(mx, __shfl_xor(mx, off, 64));
            float mn = fmaxf(m_[r], mx);
            sc[r] = __expf(m_[r] - mn);
            float ps = 0.f;
            #pragma unroll
            for (int nt = 0; nt < 4; ++nt) {
                float e = __expf(s[nt][r] - mn);
                p_[nt][r] = e; ps += e;
            }
            #pragma unroll
            for (int off = 1; off <= 8; off <<= 1) ps += __shfl_xor(ps, off, 64);
            l_[r] = l_[r] * sc[r] + ps;
            m_[r] = mn;
        }
        // C-layout -> A-layout via LDS (own rows only; no cross-wave barrier)
        #pragma unroll
        for (int nt = 0; nt < 4; ++nt)
            #pragma unroll
            for (int r = 0; r < 4; ++r)
                Ps[wave * 16 + quad * 4 + r][nt * 16 + lm] = f2bf(p_[nt][r]);

        #pragma unroll
        for (int nt = 0; nt < 4; ++nt)
            #pragma unroll
            for (int r = 0; r < 4; ++r) accO[nt][r] *= sc[r];

        bf16x8 pa0 = *(const bf16x8*)&Ps[wave * 16 + lm][quad * 8];
        bf16x8 pa1 = *(const bf16x8*)&Ps[wave * 16 + lm][32 + quad * 8];
        #pragma unroll
        for (int nt = 0; nt < 4; ++nt) {
            bf16x8 v0 = *(const bf16x8*)&Vs[nt * 16 + lm][quad * 8];
            bf16x8 v1 = *(const bf16x8*)&Vs[nt * 16 + lm][32 + quad * 8];
            accO[nt] = __builtin_amdgcn_mfma_f32_16x16x32_bf16(pa0, v0, accO[nt], 0, 0, 0);
            accO[nt] = __builtin_amdgcn_mfma_f32_16x16x32_bf16(pa1, v1, accO[nt], 0, 0, 0);
        }
    }

    #pragma unroll
    for (int r = 0; r < 4; ++r) {
        float inv = 1.0f / l_[r];
        int tok = q0 + wave * 16 + quad * 4 + r;
        #pragma unroll
        for (int nt = 0; nt < 4; ++nt)
            o[((size_t)bh * T + tok) * DH + nt * 16 + lm] = accO[nt][r] * inv;
    }
}

// ---------------- Kernel D: masked sum of attention output over T -----------
__global__ __launch_bounds__(256) void pool_kernel(
    const float* __restrict__ o, const float* __restrict__ kpmf,
    float* __restrict__ S)
{
    __shared__ float sm[4][64];
    int bh = blockIdx.x;
    int b_ = bh >> 3;
    int lane = threadIdx.x & 63, chunk = threadIdx.x >> 6;
    const float* ob = o + (size_t)bh * T * DH;
    const float* kp = kpmf + b_ * T;
    float acc = 0.f;
    for (int t = chunk * 512; t < (chunk + 1) * 512; ++t)
        acc += ob[(size_t)t * DH + lane] * (1.0f - kp[t]);
    sm[chunk][lane] = acc;
    __syncthreads();
    if (chunk == 0) {
        float r = sm[0][lane] + sm[1][lane] + sm[2][lane] + sm[3][lane];
        int h = bh & 7;
        S[b_ * D + h * DH + lane] = r;
    }
}

// ---------------- Kernel E: out-projection of pooled vector + bias ----------
__global__ __launch_bounds__(256) void out_kernel(
    const float* __restrict__ S, const float* __restrict__ kpmf,
    const float* __restrict__ Wo, const float* __restrict__ bo,
    float* __restrict__ out)
{
    __shared__ float Sl[512];
    __shared__ float cs[4];
    int b_ = blockIdx.x;
    int tid = threadIdx.x;
    Sl[tid] = S[b_ * D + tid];
    Sl[tid + 256] = S[b_ * D + tid + 256];
    const float* kp = kpmf + b_ * T;
    float c = 0.f;
    for (int t = tid; t < T; t += 256) c += kp[t];
    #pragma unroll
    for (int o = 32; o; o >>= 1) c += __shfl_xor(c, o, 64);
    if ((tid & 63) == 0) cs[tid >> 6] = c;
    __syncthreads();
    float masked = cs[0] + cs[1] + cs[2] + cs[3];
    float cnt = (float)T - masked;
    float inv = 1.0f / fmaxf(cnt, 1.0f);
    #pragma unroll
    for (int p = 0; p < 2; ++p) {
        int d = tid + p * 256;
        const float4* wr4 = (const float4*)(Wo + (size_t)d * D);
        float dot = 0.f;
        for (int k4 = 0; k4 < D / 4; ++k4) {
            float4 w4 = wr4[k4];
            dot += Sl[4 * k4 + 0] * w4.x + Sl[4 * k4 + 1] * w4.y +
                   Sl[4 * k4 + 2] * w4.z + Sl[4 * k4 + 3] * w4.w;
        }
        out[b_ * D + d] = (dot + bo[d] * cnt) * inv;
    }
}

extern "C" void kernel_launch(void* const* d_in, const int* in_sizes, int n_in,
                              void* d_out, int out_size, void* d_ws, size_t ws_size,
                              hipStream_t stream) {
    const float* embs   = (const float*)d_in[0];
    const float* labels = (const float*)d_in[1];
    const float* ln_g   = (const float*)d_in[2];
    const float* ln_b   = (const float*)d_in[3];
    const float* ipw    = (const float*)d_in[4];
    const float* ipb    = (const float*)d_in[5];
    const float* ow     = (const float*)d_in[6];
    const float* obb    = (const float*)d_in[7];
    const float* alpha  = (const float*)d_in[8];
    const float* beta   = (const float*)d_in[9];
    float* out = (float*)d_out;

    unsigned short* xb = (unsigned short*)d_ws;          // 8192*512
    unsigned short* wb = xb + (size_t)NTOK * D;          // 1536*512
    unsigned short* q  = wb + (size_t)3 * D * D;         // 8192*512
    unsigned short* k  = q  + (size_t)NTOK * D;
    unsigned short* vt = k  + (size_t)NTOK * D;
    float* o    = (float*)(vt + (size_t)NTOK * D);       // 8192*512 f32
    float* wmb  = o + (size_t)NTOK * D;                  // 8192
    float* kpmf = wmb + NTOK;                            // 8192
    float* S    = kpmf + NTOK;                           // 2048

    ln_kernel<<<NTOK, 256, 0, stream>>>(embs, labels, ln_g, ln_b, xb, wmb, kpmf);
    wconv_kernel<<<(3 * D * D) / 1024, 256, 0, stream>>>(ipw, wb);
    dim3 gq(NTOK / 64, (3 * D) / 64);
    qkv_mfma<<<gq, 256, 0, stream>>>(xb, wb, ipb, q, k, vt);
    attn_mfma<<<NB * NH * (T / 64), 256, 0, stream>>>(q, k, vt, wmb, kpmf, alpha, beta, o);
    pool_kernel<<<NB * NH, 256, 0, stream>>>(o, kpmf, S);
    out_kernel<<<NB, 256, 0, stream>>>(S, kpmf, ow, obb, out);
}